// Round 15
// baseline (179.254 us; speedup 1.0000x reference)
//
#include <hip/hip_runtime.h>

#define Bb 4
#define Ll 256
#define NEG 0.2f

typedef __attribute__((ext_vector_type(8))) short short8;
typedef __attribute__((ext_vector_type(4))) float f32x4;
typedef __attribute__((ext_vector_type(4))) unsigned uint4v;

__device__ __forceinline__ float lrelu(float x) { return x >= 0.f ? x : NEG * x; }

__device__ __forceinline__ short f2bf(float x) {
  unsigned u = __builtin_bit_cast(unsigned, x);
  unsigned r = (u + 0x7FFFu + ((u >> 16) & 1u)) >> 16;
  return (short)r;
}

// pack two f32 -> u32 of 2 bf16 (round half up); elem0 in low 16
__device__ __forceinline__ unsigned pack2bf(float e, float o) {
  unsigned ue = __builtin_bit_cast(unsigned, e);
  unsigned uo = __builtin_bit_cast(unsigned, o);
  return ((ue + 0x8000u) >> 16) | ((uo + 0x8000u) & 0xFFFF0000u);
}

// ---------------- merged prep: blocks 0..127 -> Gt (LINEAR bf16 [n][k]);
// block 128 -> Vg (fp32 [128][8], V[c*8+h]), ch(8), c0(128) ----------------
__global__ void prep_kernel(const float* We_w, const float* We_b, const float* attn_w,
                            const float* We2_w, const float* We2_b, const float* edge_w,
                            const float* edge_b, const float* out_e_w, const float* out_e_b,
                            float* Vg, float* chg, float* c0g, short* Gt) {
  int blk = blockIdx.x;
  int t = threadIdx.x; // 128 threads
  if (blk < 128) {
    __shared__ float m2[128];
    int c = blk; // k index
    int h = t >> 4, e = t & 15;
    float s = 0.f;
    for (int d = 0; d < 16; ++d) s += We2_w[c * 128 + h * 16 + d] * edge_w[d * 16 + e];
    m2[t] = s;
    __syncthreads();
    float g = 0.f;
    for (int f = 0; f < 128; ++f) g += m2[f] * out_e_w[f * 128 + t];
    Gt[t * 128 + c] = f2bf(g);
  } else {
    __shared__ float b2e[128];
    const float* we = attn_w + 64;
    for (int idx = t; idx < 1024; idx += 128) {
      int c = idx >> 3, h = idx & 7;
      float s = 0.f;
      for (int d = 0; d < 16; ++d) s += We_w[c * 128 + h * 16 + d] * we[d];
      Vg[idx] = s; // V[c*8+h]
    }
    if (t < 8) {
      float s = 0.f;
      for (int d = 0; d < 16; ++d) s += We_b[t * 16 + d] * we[d];
      chg[t] = s;
    }
    {
      int h = t >> 4, e = t & 15;
      float s = 0.f;
      for (int d = 0; d < 16; ++d) s += We2_b[h * 16 + d] * edge_w[d * 16 + e];
      b2e[t] = s + edge_b[e];
    }
    __syncthreads();
    float s = out_e_b[t];
    for (int f = 0; f < 128; ++f) s += b2e[f] * out_e_w[f * 128 + t];
    c0g[t] = s;
  }
}

// ---------------- se v3 (r13 config): 32 lanes per row, 1 float4/lane ----------------
__global__ __launch_bounds__(256) void se_kernel(const float* __restrict__ edge,
                                                 const float* __restrict__ Vg,
                                                 const float* __restrict__ chg,
                                                 float* __restrict__ se) {
  int t = threadIdx.x;
  int l32 = t & 31;
  float vreg[4][8];
#pragma unroll
  for (int ci = 0; ci < 4; ++ci)
#pragma unroll
    for (int h = 0; h < 8; ++h) vreg[ci][h] = Vg[(l32 * 4 + ci) * 8 + h];
  int hh = 4 * ((l32 >> 4) & 1) + 2 * ((l32 >> 3) & 1) + ((l32 >> 2) & 1);
  float chv = chg[hh];

  long gid = ((long)blockIdx.x * 256 + t) >> 5;
  long ngroups = ((long)gridDim.x * 256) >> 5;
  const long NR = (long)Bb * Ll * Ll;
  for (long row = gid; row < NR; row += ngroups) {
    float4 e = reinterpret_cast<const float4*>(edge + row * 128)[l32];
    float p[8];
#pragma unroll
    for (int h = 0; h < 8; ++h)
      p[h] = e.x * vreg[0][h] + e.y * vreg[1][h] + e.z * vreg[2][h] + e.w * vreg[3][h];
    bool h16 = (l32 & 16) != 0;
    float q[4];
#pragma unroll
    for (int k = 0; k < 4; ++k) {
      float keep = h16 ? p[k + 4] : p[k];
      float send = h16 ? p[k] : p[k + 4];
      q[k] = keep + __shfl_xor(send, 16);
    }
    bool h8 = (l32 & 8) != 0;
    float r2[2];
#pragma unroll
    for (int k = 0; k < 2; ++k) {
      float keep = h8 ? q[k + 2] : q[k];
      float send = h8 ? q[k] : q[k + 2];
      r2[k] = keep + __shfl_xor(send, 8);
    }
    bool h4 = (l32 & 4) != 0;
    float s = (h4 ? r2[1] : r2[0]) + __shfl_xor(h4 ? r2[0] : r2[1], 4);
    s += __shfl_xor(s, 2);
    s += __shfl_xor(s, 1);
    if ((l32 & 3) == 0) se[row * 8 + hh] = s + chv;
  }
}

// ---------------- node_in_fused: node_p = node@Wn + b; Whh; si; sj ----------------
__global__ __launch_bounds__(256) void node_in_fused(
    const float* __restrict__ node, const float* __restrict__ Wn_w,
    const float* __restrict__ Wn_b, const float* __restrict__ Wh_w,
    const float* __restrict__ Wh_b, const float* __restrict__ attn_w,
    float* __restrict__ node_p, float* __restrict__ Whh, float* __restrict__ si,
    float* __restrict__ sj) {
  __shared__ float a[4][256];
  __shared__ float np[4][256];
  int t = threadIdx.x;
  int row0 = blockIdx.x * 4;
  for (int q = t; q < 1024; q += 256) a[q >> 8][q & 255] = node[(long)row0 * 256 + q];
  __syncthreads();
  float acc[4];
  float bvv = Wn_b[t];
#pragma unroll
  for (int r = 0; r < 4; ++r) acc[r] = bvv;
  for (int k = 0; k < 256; ++k) {
    float w = Wn_w[k * 256 + t];
#pragma unroll
    for (int r = 0; r < 4; ++r) acc[r] += a[r][k] * w;
  }
#pragma unroll
  for (int r = 0; r < 4; ++r) {
    node_p[(long)(row0 + r) * 256 + t] = acc[r];
    np[r][t] = acc[r];
  }
  __syncthreads();
  int h = t >> 5, e = t & 31;
  float wb2 = Wh_b[e];
#pragma unroll
  for (int r = 0; r < 4; ++r) {
    float s = wb2;
    for (int d = 0; d < 32; ++d) s += np[r][h * 32 + d] * Wh_w[d * 32 + e];
    Whh[(long)(row0 + r) * 256 + t] = s;
  }
  if (t < 64) {
    int r = t >> 4, idx = t & 15, hh = idx & 7;
    const float* w = attn_w + (idx < 8 ? 0 : 32);
    float s = 0.f;
    for (int d = 0; d < 32; ++d) s += np[r][hh * 32 + d] * w[d];
    ((idx < 8) ? si : sj)[(long)(row0 + r) * 8 + hh] = s;
  }
}

// ---------------- attn: softmax + agg from precomputed seg ----------------
__global__ __launch_bounds__(256) void attn_fused(
    const float* __restrict__ node_p, const float* __restrict__ Whh,
    const float* __restrict__ si, const float* __restrict__ sj,
    const float* __restrict__ seg, float* __restrict__ node_h) {
  __shared__ float sjl[2048];
  __shared__ float sel[2048];
  __shared__ float pl[2048];
  __shared__ float sil[8];
  int t = threadIdx.x, bi = blockIdx.x;
  int b = bi >> 8, i = bi & 255;
  for (int q = t; q < 2048; q += 256) sjl[q] = sj[(long)b * 2048 + q];
  for (int q = t; q < 2048; q += 256) sel[q] = seg[(long)bi * 2048 + q];
  if (t < 8) sil[t] = si[(long)bi * 8 + t];
  __syncthreads();

  int g = t >> 5, l32 = t & 31;
  float sc[8];
  float mx = -1e30f;
#pragma unroll
  for (int m = 0; m < 8; ++m) {
    int k = l32 + 32 * m;
    float v = -1e30f;
    if (k < 255) {
      int jj = k + (k >= i ? 1 : 0);
      v = sil[g] + sjl[jj * 8 + g] + sel[jj * 8 + g];
      v = lrelu(v);
    }
    sc[m] = v;
    mx = fmaxf(mx, v);
  }
#pragma unroll
  for (int d = 16; d >= 1; d >>= 1) mx = fmaxf(mx, __shfl_xor(mx, d));
  float sum = 0.f;
#pragma unroll
  for (int m = 0; m < 8; ++m) {
    int k = l32 + 32 * m;
    float e = (k < 255) ? __expf(sc[m] - mx) : 0.f;
    sc[m] = e;
    sum += e;
  }
#pragma unroll
  for (int d = 16; d >= 1; d >>= 1) sum += __shfl_xor(sum, d);
  float inv = 1.f / sum;
#pragma unroll
  for (int m = 0; m < 8; ++m) {
    int k = l32 + 32 * m;
    if (k < 255) pl[k * 8 + g] = sc[m] * inv;
  }
  __syncthreads();

  int h = g;
  const float* wb = Whh + (long)b * 65536 + t;
  float acc0 = 0.f, acc1 = 0.f;
#pragma unroll 8
  for (int j = 0; j < 256; j += 2) {
    int k0 = (j == 0) ? 254 : (j - 1);
    int k1 = j;
    float w0 = (j == i) ? 0.f : pl[k0 * 8 + h];
    float w1 = (j + 1 == i) ? 0.f : pl[k1 * 8 + h];
    acc0 += w0 * wb[(long)j * 256];
    acc1 += w1 * wb[(long)(j + 1) * 256];
  }
  float acc = acc0 + acc1;
  float np = node_p[(long)bi * 256 + t];
  node_h[(long)bi * 256 + t] = np + lrelu(acc);
}

// ---------------- node_out_pq: out_node; node_p2; P/Q ----------------
__global__ __launch_bounds__(256) void node_out_pq(
    const float* __restrict__ node_h, const float* __restrict__ out_n_w,
    const float* __restrict__ out_n_b, const float* __restrict__ Wn2_w,
    const float* __restrict__ Wn2_b, const float* __restrict__ edge_w,
    const float* __restrict__ out_e_w, float* __restrict__ out_node,
    float* __restrict__ Pg, float* __restrict__ Qg) {
  __shared__ float a[4][256];
  __shared__ float b2[4][256];
  __shared__ float ninj[4][256];
  int t = threadIdx.x;
  int row0 = blockIdx.x * 4;
  for (int q = t; q < 1024; q += 256) a[q >> 8][q & 255] = node_h[(long)row0 * 256 + q];
  __syncthreads();
  float acc[4];
  float bv1 = out_n_b[t];
#pragma unroll
  for (int r = 0; r < 4; ++r) acc[r] = bv1;
  for (int k = 0; k < 256; ++k) {
    float w = out_n_w[k * 256 + t];
#pragma unroll
    for (int r = 0; r < 4; ++r) acc[r] += a[r][k] * w;
  }
#pragma unroll
  for (int r = 0; r < 4; ++r) {
    out_node[(long)(row0 + r) * 256 + t] = acc[r];
    b2[r][t] = acc[r];
  }
  __syncthreads();
  float acc2[4];
  float bv2 = Wn2_b[t];
#pragma unroll
  for (int r = 0; r < 4; ++r) acc2[r] = bv2;
  for (int k = 0; k < 256; ++k) {
    float w = Wn2_w[k * 256 + t];
#pragma unroll
    for (int r = 0; r < 4; ++r) acc2[r] += b2[r][k] * w;
  }
#pragma unroll
  for (int r = 0; r < 4; ++r) a[r][t] = acc2[r]; // node_p2
  __syncthreads();
  {
    int f = t & 127, h = f >> 4, e = f & 15;
    const float* w = edge_w + 256 + (t >> 7) * 512; // w_i / w_j
#pragma unroll
    for (int r = 0; r < 4; ++r) {
      float s = 0.f;
      for (int d = 0; d < 32; ++d) s += a[r][h * 32 + d] * w[d * 16 + e];
      ninj[r][t] = s;
    }
  }
  __syncthreads();
  {
    int o = t & 127;
    int half = (t >> 7) * 128;
#pragma unroll
    for (int r = 0; r < 4; ++r) {
      float s = 0.f;
      const float* src = ninj[r] + half;
      for (int f = 0; f < 128; ++f) s += src[f] * out_e_w[f * 128 + o];
      ((t < 128) ? Pg : Qg)[(long)(row0 + r) * 128 + o] = s;
    }
  }
}

// ---------------- edge_out v10: depth-2 prefetch, 3 LDS buffers, counted vmcnt.
// 1024 blocks x 8 tiles of 32x128; all tiles of a block share bi = blockIdx.x.
// Per-iter: stage(t+2) | compute(t) | certify stage(t+1) via counted vmcnt | barrier |
// epilogue(t). Counts shaded down 4 for slack (extra stall-safe, race-free).
#define TPB_E 8
__global__ __launch_bounds__(256, 3) void edge_out_kernel(
    const float* __restrict__ edge, const short* __restrict__ Gt,
    const float* __restrict__ Pg, const float* __restrict__ Qg,
    const float* __restrict__ c0g, const float* __restrict__ oeb,
    float* __restrict__ out_edge) {
  __shared__ __align__(16) float abuf[3][32 * 128]; // 3 x 16 KB, row-swizzled image
  int t = threadIdx.x;
  int l = t & 63, wid = t >> 6;
  int wm = wid >> 1, wn = wid & 1;
  int lc = l & 15, lq = l >> 4;

  // G fragments in registers (linear Gt)
  short8 bv[4][4];
#pragma unroll
  for (int ks = 0; ks < 4; ++ks)
#pragma unroll
    for (int nf = 0; nf < 4; ++nf)
      bv[ks][nf] = *(const short8*)(Gt + (wn * 64 + nf * 16 + lc) * 128 + ks * 32 + lq * 8);

  int bi = blockIdx.x;
  int b = bi >> 8, i = bi & 255;

  float oebv[4], pcv[4];
#pragma unroll
  for (int nf = 0; nf < 4; ++nf) {
    int col = wn * 64 + nf * 16 + lc;
    oebv[nf] = oeb[col];
    pcv[nf] = Pg[(long)bi * 128 + col] + c0g[col];
  }

  long tile0 = (long)blockIdx.x * TPB_E;

  auto stage = [&](int buf, long tile) {
#pragma unroll
    for (int q = 0; q < 4; ++q) {
      int L = q * 256 + t; // 16B chunk index
      int row = L >> 5, c4 = L & 31;
      int scol = (c4 * 4) ^ ((row & 7) << 2); // float index within row
      const float* gp = edge + (tile * 32 + row) * 128 + scol;
      char* lp = (char*)abuf[buf] + q * 4096 + wid * 1024;
      __builtin_amdgcn_global_load_lds(
          (const __attribute__((address_space(1))) unsigned*)gp,
          (__attribute__((address_space(3))) unsigned*)lp, 16, 0, 0);
    }
  };

  // prologue: two tiles in flight; certify tile0 (8 outstanding -> <=4)
  stage(0, tile0);
  stage(1, tile0 + 1);
  asm volatile("s_waitcnt vmcnt(4)" ::: "memory");
  __builtin_amdgcn_s_barrier();
  asm volatile("" ::: "memory");

#pragma unroll
  for (int tt = 0; tt < TPB_E; ++tt) {
    // issue depth-2 prefetch into the buffer freed by compute(tt-1)
    if (tt + 2 < TPB_E) stage((tt + 2) % 3, tile0 + tt + 2);
    asm volatile("" ::: "memory");

    int row0loc = tt * 32;
    const char* rbase = (const char*)abuf[tt % 3] + (wm * 16 + lc) * 512;
    int sw = ((wm * 16 + lc) & 7) << 4;

    f32x4 acc[4];
#pragma unroll
    for (int nf = 0; nf < 4; ++nf) acc[nf] = (f32x4){0.f, 0.f, 0.f, 0.f};
#pragma unroll
    for (int ks = 0; ks < 4; ++ks) {
      int cb = ks * 128 + lq * 32;
      float4 f0 = *(const float4*)(rbase + (cb ^ sw));
      float4 f1 = *(const float4*)(rbase + ((cb + 16) ^ sw));
      uint4v u;
      u.x = pack2bf(f0.x, f0.y);
      u.y = pack2bf(f0.z, f0.w);
      u.z = pack2bf(f1.x, f1.y);
      u.w = pack2bf(f1.z, f1.w);
      short8 av = __builtin_bit_cast(short8, u);
#pragma unroll
      for (int nf = 0; nf < 4; ++nf)
        acc[nf] = __builtin_amdgcn_mfma_f32_16x16x32_bf16(av, bv[ks][nf], acc[nf], 0, 0, 0);
    }
    asm volatile("" ::: "memory");

    // certify stage(tt+1) before next iter's compute; never drain stores.
    // ops issued after stage(tt+1): epilogue(tt-1) (32: 16 Q-loads + 16 stores,
    // only when tt>=1) + stage(tt+2) (4, when present). Shade down by 4.
    if (tt == 0) {
      asm volatile("s_waitcnt vmcnt(4)" ::: "memory"); // after: stage(2) only
    } else if (tt + 2 < TPB_E) {
      asm volatile("s_waitcnt vmcnt(32)" ::: "memory"); // after: 32 epi + 4 stage
    } else if (tt + 1 < TPB_E) {
      asm volatile("s_waitcnt vmcnt(28)" ::: "memory"); // after: 32 epi only
    }
    if (tt + 1 < TPB_E) {
      __builtin_amdgcn_s_barrier();
      asm volatile("" ::: "memory");
    }

    // epilogue for tile tt (global Q loads + stores; behind the barrier)
#pragma unroll
    for (int r = 0; r < 4; ++r) {
      int jloc = row0loc + wm * 16 + lq * 4 + r;
      float* orow = out_edge + ((long)bi * 256 + jloc) * 128;
      const float* Qrow = Qg + (long)(b * 256 + jloc) * 128;
      bool diag = (jloc == i);
#pragma unroll
      for (int nf = 0; nf < 4; ++nf) {
        int col = wn * 64 + nf * 16 + lc;
        float v = diag ? oebv[nf] : (acc[nf][r] + pcv[nf] + Qrow[col]);
        orow[col] = v;
      }
    }
    asm volatile("" ::: "memory");
  }
}

extern "C" void kernel_launch(void* const* d_in, const int* in_sizes, int n_in,
                              void* d_out, int out_size, void* d_ws, size_t ws_size,
                              hipStream_t stream) {
  const float* node = (const float*)d_in[0];
  const float* edge = (const float*)d_in[1];
  const float* Wn_w = (const float*)d_in[2];
  const float* Wn_b = (const float*)d_in[3];
  const float* Wh_w = (const float*)d_in[4];
  const float* Wh_b = (const float*)d_in[5];
  const float* We_w = (const float*)d_in[6];
  const float* We_b = (const float*)d_in[7];
  const float* Wn2_w = (const float*)d_in[8];
  const float* Wn2_b = (const float*)d_in[9];
  const float* We2_w = (const float*)d_in[10];
  const float* We2_b = (const float*)d_in[11];
  const float* attn_w = (const float*)d_in[12];
  const float* edge_w = (const float*)d_in[13];
  const float* edge_b = (const float*)d_in[14];
  const float* out_n_w = (const float*)d_in[15];
  const float* out_n_b = (const float*)d_in[16];
  const float* out_e_w = (const float*)d_in[17];
  const float* out_e_b = (const float*)d_in[18];

  float* out_node = (float*)d_out;            // 262144
  float* out_edge = ((float*)d_out) + 262144; // 33554432

  float* ws = (float*)d_ws;
  float* node_p = ws;                      // 262144
  float* Whh    = ws + 262144;             // 262144
  float* node_h = ws + 524288;             // 262144
  float* si     = ws + 786432;             // 8192
  float* sjv    = ws + 794624;             // 8192
  float* Pg     = ws + 802816;             // 131072
  float* Qg     = ws + 933888;             // 131072
  float* chg    = ws + 1064960;            // 128
  float* c0g    = ws + 1065088;            // 128
  short* Gt     = (short*)(ws + 1065216);  // 16384 shorts
  float* Vg     = ws + 1073408;            // 1024
  float* seg    = ws + 1074432;            // 2097152

  prep_kernel<<<129, 128, 0, stream>>>(We_w, We_b, attn_w, We2_w, We2_b, edge_w, edge_b,
                                       out_e_w, out_e_b, Vg, chg, c0g, Gt);
  node_in_fused<<<256, 256, 0, stream>>>(node, Wn_w, Wn_b, Wh_w, Wh_b, attn_w, node_p, Whh,
                                         si, sjv);
  se_kernel<<<2048, 256, 0, stream>>>(edge, Vg, chg, seg);
  attn_fused<<<1024, 256, 0, stream>>>(node_p, Whh, si, sjv, seg, node_h);
  node_out_pq<<<256, 256, 0, stream>>>(node_h, out_n_w, out_n_b, Wn2_w, Wn2_b, edge_w,
                                       out_e_w, out_node, Pg, Qg);
  edge_out_kernel<<<1024, 256, 0, stream>>>(edge, Gt, Pg, Qg, c0g, out_e_b, out_edge);
}

// Round 16
// 158.977 us; speedup vs baseline: 1.1275x; 1.1275x over previous
//
#include <hip/hip_runtime.h>

#define Bb 4
#define Ll 256
#define NEG 0.2f

typedef __attribute__((ext_vector_type(8))) short short8;
typedef __attribute__((ext_vector_type(4))) float f32x4;
typedef __attribute__((ext_vector_type(4))) unsigned uint4v;

__device__ __forceinline__ float lrelu(float x) { return x >= 0.f ? x : NEG * x; }

__device__ __forceinline__ short f2bf(float x) {
  unsigned u = __builtin_bit_cast(unsigned, x);
  unsigned r = (u + 0x7FFFu + ((u >> 16) & 1u)) >> 16;
  return (short)r;
}

// pack two f32 -> u32 of 2 bf16 (round half up); elem0 in low 16
__device__ __forceinline__ unsigned pack2bf(float e, float o) {
  unsigned ue = __builtin_bit_cast(unsigned, e);
  unsigned uo = __builtin_bit_cast(unsigned, o);
  return ((ue + 0x8000u) >> 16) | ((uo + 0x8000u) & 0xFFFF0000u);
}

// ---------------- merged prep: blocks 0..127 -> Gt (LINEAR bf16 [n][k]);
// block 128 -> Vg (fp32 [128][8], V[c*8+h]), ch(8), c0(128) ----------------
__global__ void prep_kernel(const float* We_w, const float* We_b, const float* attn_w,
                            const float* We2_w, const float* We2_b, const float* edge_w,
                            const float* edge_b, const float* out_e_w, const float* out_e_b,
                            float* Vg, float* chg, float* c0g, short* Gt) {
  int blk = blockIdx.x;
  int t = threadIdx.x; // 128 threads
  if (blk < 128) {
    __shared__ float m2[128];
    int c = blk; // k index
    int h = t >> 4, e = t & 15;
    float s = 0.f;
    for (int d = 0; d < 16; ++d) s += We2_w[c * 128 + h * 16 + d] * edge_w[d * 16 + e];
    m2[t] = s;
    __syncthreads();
    float g = 0.f;
    for (int f = 0; f < 128; ++f) g += m2[f] * out_e_w[f * 128 + t];
    Gt[t * 128 + c] = f2bf(g);
  } else {
    __shared__ float b2e[128];
    const float* we = attn_w + 64;
    for (int idx = t; idx < 1024; idx += 128) {
      int c = idx >> 3, h = idx & 7;
      float s = 0.f;
      for (int d = 0; d < 16; ++d) s += We_w[c * 128 + h * 16 + d] * we[d];
      Vg[idx] = s; // V[c*8+h]
    }
    if (t < 8) {
      float s = 0.f;
      for (int d = 0; d < 16; ++d) s += We_b[t * 16 + d] * we[d];
      chg[t] = s;
    }
    {
      int h = t >> 4, e = t & 15;
      float s = 0.f;
      for (int d = 0; d < 16; ++d) s += We2_b[h * 16 + d] * edge_w[d * 16 + e];
      b2e[t] = s + edge_b[e];
    }
    __syncthreads();
    float s = out_e_b[t];
    for (int f = 0; f < 128; ++f) s += b2e[f] * out_e_w[f * 128 + t];
    c0g[t] = s;
  }
}

// ---------------- se v3: 32 lanes per row, 1 float4/lane, low VGPR, max occupancy ----
__global__ __launch_bounds__(256) void se_kernel(const float* __restrict__ edge,
                                                 const float* __restrict__ Vg,
                                                 const float* __restrict__ chg,
                                                 float* __restrict__ se) {
  int t = threadIdx.x;
  int l32 = t & 31;
  // each lane owns cols [l32*4, l32*4+4)
  float vreg[4][8];
#pragma unroll
  for (int ci = 0; ci < 4; ++ci)
#pragma unroll
    for (int h = 0; h < 8; ++h) vreg[ci][h] = Vg[(l32 * 4 + ci) * 8 + h];
  int hh = 4 * ((l32 >> 4) & 1) + 2 * ((l32 >> 3) & 1) + ((l32 >> 2) & 1);
  float chv = chg[hh];

  long gid = ((long)blockIdx.x * 256 + t) >> 5; // 32-lane group id
  long ngroups = ((long)gridDim.x * 256) >> 5;
  const long NR = (long)Bb * Ll * Ll;
  for (long row = gid; row < NR; row += ngroups) {
    float4 e = reinterpret_cast<const float4*>(edge + row * 128)[l32];
    float p[8];
#pragma unroll
    for (int h = 0; h < 8; ++h)
      p[h] = e.x * vreg[0][h] + e.y * vreg[1][h] + e.z * vreg[2][h] + e.w * vreg[3][h];
    bool h16 = (l32 & 16) != 0;
    float q[4];
#pragma unroll
    for (int k = 0; k < 4; ++k) {
      float keep = h16 ? p[k + 4] : p[k];
      float send = h16 ? p[k] : p[k + 4];
      q[k] = keep + __shfl_xor(send, 16);
    }
    bool h8 = (l32 & 8) != 0;
    float r2[2];
#pragma unroll
    for (int k = 0; k < 2; ++k) {
      float keep = h8 ? q[k + 2] : q[k];
      float send = h8 ? q[k] : q[k + 2];
      r2[k] = keep + __shfl_xor(send, 8);
    }
    bool h4 = (l32 & 4) != 0;
    float s = (h4 ? r2[1] : r2[0]) + __shfl_xor(h4 ? r2[0] : r2[1], 4);
    s += __shfl_xor(s, 2);
    s += __shfl_xor(s, 1);
    if ((l32 & 3) == 0) se[row * 8 + hh] = s + chv;
  }
}

// ---------------- node_in_fused: node_p = node@Wn + b; Whh; si; sj ----------------
__global__ __launch_bounds__(256) void node_in_fused(
    const float* __restrict__ node, const float* __restrict__ Wn_w,
    const float* __restrict__ Wn_b, const float* __restrict__ Wh_w,
    const float* __restrict__ Wh_b, const float* __restrict__ attn_w,
    float* __restrict__ node_p, float* __restrict__ Whh, float* __restrict__ si,
    float* __restrict__ sj) {
  __shared__ float a[4][256];
  __shared__ float np[4][256];
  int t = threadIdx.x;
  int row0 = blockIdx.x * 4;
  for (int q = t; q < 1024; q += 256) a[q >> 8][q & 255] = node[(long)row0 * 256 + q];
  __syncthreads();
  float acc[4];
  float bvv = Wn_b[t];
#pragma unroll
  for (int r = 0; r < 4; ++r) acc[r] = bvv;
  for (int k = 0; k < 256; ++k) {
    float w = Wn_w[k * 256 + t];
#pragma unroll
    for (int r = 0; r < 4; ++r) acc[r] += a[r][k] * w;
  }
#pragma unroll
  for (int r = 0; r < 4; ++r) {
    node_p[(long)(row0 + r) * 256 + t] = acc[r];
    np[r][t] = acc[r];
  }
  __syncthreads();
  int h = t >> 5, e = t & 31;
  float wb2 = Wh_b[e];
#pragma unroll
  for (int r = 0; r < 4; ++r) {
    float s = wb2;
    for (int d = 0; d < 32; ++d) s += np[r][h * 32 + d] * Wh_w[d * 32 + e];
    Whh[(long)(row0 + r) * 256 + t] = s;
  }
  if (t < 64) {
    int r = t >> 4, idx = t & 15, hh = idx & 7;
    const float* w = attn_w + (idx < 8 ? 0 : 32);
    float s = 0.f;
    for (int d = 0; d < 32; ++d) s += np[r][hh * 32 + d] * w[d];
    ((idx < 8) ? si : sj)[(long)(row0 + r) * 8 + hh] = s;
  }
}

// ---------------- attn: softmax + agg from precomputed seg ----------------
__global__ __launch_bounds__(256) void attn_fused(
    const float* __restrict__ node_p, const float* __restrict__ Whh,
    const float* __restrict__ si, const float* __restrict__ sj,
    const float* __restrict__ seg, float* __restrict__ node_h) {
  __shared__ float sjl[2048];
  __shared__ float sel[2048];
  __shared__ float pl[2048];
  __shared__ float sil[8];
  int t = threadIdx.x, bi = blockIdx.x;
  int b = bi >> 8, i = bi & 255;
  for (int q = t; q < 2048; q += 256) sjl[q] = sj[(long)b * 2048 + q];
  for (int q = t; q < 2048; q += 256) sel[q] = seg[(long)bi * 2048 + q];
  if (t < 8) sil[t] = si[(long)bi * 8 + t];
  __syncthreads();

  int g = t >> 5, l32 = t & 31;
  float sc[8];
  float mx = -1e30f;
#pragma unroll
  for (int m = 0; m < 8; ++m) {
    int k = l32 + 32 * m;
    float v = -1e30f;
    if (k < 255) {
      int jj = k + (k >= i ? 1 : 0);
      v = sil[g] + sjl[jj * 8 + g] + sel[jj * 8 + g];
      v = lrelu(v);
    }
    sc[m] = v;
    mx = fmaxf(mx, v);
  }
#pragma unroll
  for (int d = 16; d >= 1; d >>= 1) mx = fmaxf(mx, __shfl_xor(mx, d));
  float sum = 0.f;
#pragma unroll
  for (int m = 0; m < 8; ++m) {
    int k = l32 + 32 * m;
    float e = (k < 255) ? __expf(sc[m] - mx) : 0.f;
    sc[m] = e;
    sum += e;
  }
#pragma unroll
  for (int d = 16; d >= 1; d >>= 1) sum += __shfl_xor(sum, d);
  float inv = 1.f / sum;
#pragma unroll
  for (int m = 0; m < 8; ++m) {
    int k = l32 + 32 * m;
    if (k < 255) pl[k * 8 + g] = sc[m] * inv;
  }
  __syncthreads();

  int h = g;
  const float* wb = Whh + (long)b * 65536 + t;
  float acc0 = 0.f, acc1 = 0.f;
#pragma unroll 8
  for (int j = 0; j < 256; j += 2) {
    int k0 = (j == 0) ? 254 : (j - 1);
    int k1 = j;
    float w0 = (j == i) ? 0.f : pl[k0 * 8 + h];
    float w1 = (j + 1 == i) ? 0.f : pl[k1 * 8 + h];
    acc0 += w0 * wb[(long)j * 256];
    acc1 += w1 * wb[(long)(j + 1) * 256];
  }
  float acc = acc0 + acc1;
  float np = node_p[(long)bi * 256 + t];
  node_h[(long)bi * 256 + t] = np + lrelu(acc);
}

// ---------------- node_out_pq: out_node; node_p2; P/Q ----------------
__global__ __launch_bounds__(256) void node_out_pq(
    const float* __restrict__ node_h, const float* __restrict__ out_n_w,
    const float* __restrict__ out_n_b, const float* __restrict__ Wn2_w,
    const float* __restrict__ Wn2_b, const float* __restrict__ edge_w,
    const float* __restrict__ out_e_w, float* __restrict__ out_node,
    float* __restrict__ Pg, float* __restrict__ Qg) {
  __shared__ float a[4][256];
  __shared__ float b2[4][256];
  __shared__ float ninj[4][256];
  int t = threadIdx.x;
  int row0 = blockIdx.x * 4;
  for (int q = t; q < 1024; q += 256) a[q >> 8][q & 255] = node_h[(long)row0 * 256 + q];
  __syncthreads();
  float acc[4];
  float bv1 = out_n_b[t];
#pragma unroll
  for (int r = 0; r < 4; ++r) acc[r] = bv1;
  for (int k = 0; k < 256; ++k) {
    float w = out_n_w[k * 256 + t];
#pragma unroll
    for (int r = 0; r < 4; ++r) acc[r] += a[r][k] * w;
  }
#pragma unroll
  for (int r = 0; r < 4; ++r) {
    out_node[(long)(row0 + r) * 256 + t] = acc[r];
    b2[r][t] = acc[r];
  }
  __syncthreads();
  float acc2[4];
  float bv2 = Wn2_b[t];
#pragma unroll
  for (int r = 0; r < 4; ++r) acc2[r] = bv2;
  for (int k = 0; k < 256; ++k) {
    float w = Wn2_w[k * 256 + t];
#pragma unroll
    for (int r = 0; r < 4; ++r) acc2[r] += b2[r][k] * w;
  }
#pragma unroll
  for (int r = 0; r < 4; ++r) a[r][t] = acc2[r]; // node_p2
  __syncthreads();
  {
    int f = t & 127, h = f >> 4, e = f & 15;
    const float* w = edge_w + 256 + (t >> 7) * 512; // w_i / w_j
#pragma unroll
    for (int r = 0; r < 4; ++r) {
      float s = 0.f;
      for (int d = 0; d < 32; ++d) s += a[r][h * 32 + d] * w[d * 16 + e];
      ninj[r][t] = s;
    }
  }
  __syncthreads();
  {
    int o = t & 127;
    int half = (t >> 7) * 128;
#pragma unroll
    for (int r = 0; r < 4; ++r) {
      float s = 0.f;
      const float* src = ninj[r] + half;
      for (int f = 0; f < 128; ++f) s += src[f] * out_e_w[f * 128 + o];
      ((t < 128) ? Pg : Qg)[(long)(row0 + r) * 128 + o] = s;
    }
  }
}

// ---------------- edge_out v8: persistent blocks, gload_lds staging, counted-vmcnt
// pipeline (raw s_barrier, no mid-loop drain). 1024 blocks x 8 tiles of 32x128.
// Wave = 16 rows x 64 cols. D[row=lq*4+r][col=nf*16+lc] (v7-verified mapping).
#define TPB_E 8
__global__ __launch_bounds__(256, 3) void edge_out_kernel(
    const float* __restrict__ edge, const short* __restrict__ Gt,
    const float* __restrict__ Pg, const float* __restrict__ Qg,
    const float* __restrict__ c0g, const float* __restrict__ oeb,
    float* __restrict__ out_edge) {
  __shared__ __align__(16) float abuf[2][32 * 128]; // 2 x 16 KB, row-swizzled image
  int t = threadIdx.x;
  int l = t & 63, wid = t >> 6;
  int wm = wid >> 1, wn = wid & 1;
  int lc = l & 15, lq = l >> 4;

  // G fragments in registers (linear Gt)
  short8 bv[4][4];
#pragma unroll
  for (int ks = 0; ks < 4; ++ks)
#pragma unroll
    for (int nf = 0; nf < 4; ++nf)
      bv[ks][nf] = *(const short8*)(Gt + (wn * 64 + nf * 16 + lc) * 128 + ks * 32 + lq * 8);

  float oebv[4];
#pragma unroll
  for (int nf = 0; nf < 4; ++nf) oebv[nf] = oeb[wn * 64 + nf * 16 + lc];

  long tile0 = (long)blockIdx.x * TPB_E;

  auto stage = [&](int buf, long tile) {
#pragma unroll
    for (int q = 0; q < 4; ++q) {
      int L = q * 256 + t; // 16B chunk index
      int row = L >> 5, c4 = L & 31;
      int scol = (c4 * 4) ^ ((row & 7) << 2); // float index within row
      const float* gp = edge + (tile * 32 + row) * 128 + scol;
      char* lp = (char*)abuf[buf] + q * 4096 + wid * 1024;
      __builtin_amdgcn_global_load_lds(
          (const __attribute__((address_space(1))) unsigned*)gp,
          (__attribute__((address_space(3))) unsigned*)lp, 16, 0, 0);
    }
  };

  stage(0, tile0);
  __syncthreads(); // prologue: full drain once

  int cur = 0;
  for (int tt = 0; tt < TPB_E; ++tt) {
    long tile = tile0 + tt;
    if (tt + 1 < TPB_E) stage(cur ^ 1, tile + 1);

    int bi = (int)(tile >> 3);
    int b = bi >> 8, i = bi & 255;
    int row0loc = (int)(tile & 7) * 32;

    float pcv[4];
#pragma unroll
    for (int nf = 0; nf < 4; ++nf) {
      int col = wn * 64 + nf * 16 + lc;
      pcv[nf] = Pg[(long)bi * 128 + col] + c0g[col];
    }

    const char* rbase = (const char*)abuf[cur] + (wm * 16 + lc) * 512;
    int sw = ((wm * 16 + lc) & 7) << 4;

    f32x4 acc[4];
#pragma unroll
    for (int nf = 0; nf < 4; ++nf) acc[nf] = (f32x4){0.f, 0.f, 0.f, 0.f};
#pragma unroll
    for (int ks = 0; ks < 4; ++ks) {
      int cb = ks * 128 + lq * 32;
      float4 f0 = *(const float4*)(rbase + (cb ^ sw));
      float4 f1 = *(const float4*)(rbase + ((cb + 16) ^ sw));
      uint4v u;
      u.x = pack2bf(f0.x, f0.y);
      u.y = pack2bf(f0.z, f0.w);
      u.z = pack2bf(f1.x, f1.y);
      u.w = pack2bf(f1.z, f1.w);
      short8 av = __builtin_bit_cast(short8, u);
#pragma unroll
      for (int nf = 0; nf < 4; ++nf)
        acc[nf] = __builtin_amdgcn_mfma_f32_16x16x32_bf16(av, bv[ks][nf], acc[nf], 0, 0, 0);
    }

#pragma unroll
    for (int r = 0; r < 4; ++r) {
      int jloc = row0loc + wm * 16 + lq * 4 + r;
      float* orow = out_edge + ((long)bi * 256 + jloc) * 128;
      const float* Qrow = Qg + (long)(b * 256 + jloc) * 128;
      bool diag = (jloc == i);
#pragma unroll
      for (int nf = 0; nf < 4; ++nf) {
        int col = wn * 64 + nf * 16 + lc;
        float v = diag ? oebv[nf] : (acc[nf][r] + pcv[nf] + Qrow[col]);
        orow[col] = v;
      }
    }

    asm volatile("s_waitcnt vmcnt(16)" ::: "memory");
    __builtin_amdgcn_s_barrier();
    asm volatile("" ::: "memory");
    cur ^= 1;
  }
}

extern "C" void kernel_launch(void* const* d_in, const int* in_sizes, int n_in,
                              void* d_out, int out_size, void* d_ws, size_t ws_size,
                              hipStream_t stream) {
  const float* node = (const float*)d_in[0];
  const float* edge = (const float*)d_in[1];
  const float* Wn_w = (const float*)d_in[2];
  const float* Wn_b = (const float*)d_in[3];
  const float* Wh_w = (const float*)d_in[4];
  const float* Wh_b = (const float*)d_in[5];
  const float* We_w = (const float*)d_in[6];
  const float* We_b = (const float*)d_in[7];
  const float* Wn2_w = (const float*)d_in[8];
  const float* Wn2_b = (const float*)d_in[9];
  const float* We2_w = (const float*)d_in[10];
  const float* We2_b = (const float*)d_in[11];
  const float* attn_w = (const float*)d_in[12];
  const float* edge_w = (const float*)d_in[13];
  const float* edge_b = (const float*)d_in[14];
  const float* out_n_w = (const float*)d_in[15];
  const float* out_n_b = (const float*)d_in[16];
  const float* out_e_w = (const float*)d_in[17];
  const float* out_e_b = (const float*)d_in[18];

  float* out_node = (float*)d_out;            // 262144
  float* out_edge = ((float*)d_out) + 262144; // 33554432

  float* ws = (float*)d_ws;
  float* node_p = ws;                      // 262144
  float* Whh    = ws + 262144;             // 262144
  float* node_h = ws + 524288;             // 262144
  float* si     = ws + 786432;             // 8192
  float* sjv    = ws + 794624;             // 8192
  float* Pg     = ws + 802816;             // 131072
  float* Qg     = ws + 933888;             // 131072
  float* chg    = ws + 1064960;            // 128
  float* c0g    = ws + 1065088;            // 128
  short* Gt     = (short*)(ws + 1065216);  // 16384 shorts
  float* Vg     = ws + 1073408;            // 1024
  float* seg    = ws + 1074432;            // 2097152

  prep_kernel<<<129, 128, 0, stream>>>(We_w, We_b, attn_w, We2_w, We2_b, edge_w, edge_b,
                                       out_e_w, out_e_b, Vg, chg, c0g, Gt);
  node_in_fused<<<256, 256, 0, stream>>>(node, Wn_w, Wn_b, Wh_w, Wh_b, attn_w, node_p, Whh,
                                         si, sjv);
  se_kernel<<<2048, 256, 0, stream>>>(edge, Vg, chg, seg);
  attn_fused<<<1024, 256, 0, stream>>>(node_p, Whh, si, sjv, seg, node_h);
  node_out_pq<<<256, 256, 0, stream>>>(node_h, out_n_w, out_n_b, Wn2_w, Wn2_b, edge_w,
                                       out_e_w, out_node, Pg, Qg);
  edge_out_kernel<<<1024, 256, 0, stream>>>(edge, Gt, Pg, Qg, c0g, out_e_b, out_edge);
}